// Round 14
// baseline (176.781 us; speedup 1.0000x reference)
//
#include <hip/hip_runtime.h>
#include <hip/hip_bf16.h>
#include <hip/hip_cooperative_groups.h>
#include <cstdint>

// Problem constants
#define SDIM 160
#define HDIM 768
#define HALF 384
#define ODIM 260
#define OPAD 272           // 17 * 16
#define CHUNK_BYTES 34816  // 8 kgroups * 272 rows * 16B (W2b chunk)
#define RT_CHUNK 4096      // 8 kgroups * 32 j * 16B (Rt chunk slab)
#define BUF_STRIDE 38912   // CHUNK_BYTES + RT_CHUNK
#define LB_OFF 77824       // 2 * BUF_STRIDE
// main LDS = 77824 + 3072 = 80896; 2 blocks/CU (161792 <= 163840)
// Workspace layout (bytes): pad@0(16) yb@16 Lb@245776 Rt@491536 W2b@737296
//                           W1b@1155088 end@3514384
#define WS_SMALL 1155088
#define WS_BIG   3514384

typedef __attribute__((ext_vector_type(8))) short short8;
typedef __attribute__((ext_vector_type(4))) float floatx4;
typedef _Float16 half8 __attribute__((ext_vector_type(8)));

typedef const __attribute__((address_space(1))) unsigned char gl_u8;
typedef __attribute__((address_space(3))) unsigned char lds_u8;

namespace cg = cooperative_groups;

static __device__ __forceinline__ float bf2f(unsigned short u) {
    union { unsigned int i; float f; } v; v.i = ((unsigned int)u) << 16; return v.f;
}
static __device__ __forceinline__ unsigned short f2bf(float x) {
    __hip_bfloat16 h = __float2bfloat16(x);
    return *reinterpret_cast<unsigned short*>(&h);
}
static __device__ __forceinline__ unsigned short f2h(float x) {
    _Float16 h = (_Float16)x;
    return *reinterpret_cast<unsigned short*>(&h);
}
static __device__ __forceinline__ float q(float x) { return bf2f(f2bf(x)); }

// ---------------------------------------------------------------------------
// Kernel A (R34): cooperative fusion of prep + lr3, STAGED design (big path).
// WHY: cross-round fit gives total = 70.7 + main for 3-launch rounds; R1's
// 2-launch coop round fit 63.9 + kernels -> one launch boundary costs
// ~6.8us, larger than prep+lr3 combined (~5us). R1's fused kernel itself
// was slow ONLY because phase 1 had 7680 threads and phase 2 used unstaged
// W1-direct gathers. THIS version: phase 1 = exact prep conversions
// (RoPE->yb, W2->W2b, W1->W1b) spread over 122880 threads (~1.2 slots/thr);
// grid.sync(); phase 2 = exact lr3 body, one (mt,sq) unit per wave for
// waves 0-1 of each block (960 units, ~3.75 waves/CU = proven occupancy).
// Same formulas + same K-accumulation chains -> same output (R1 precedent:
// fusion pattern passed with identical absmax).
// ---------------------------------------------------------------------------
__global__ __launch_bounds__(256) void fused_pl_kernel(
    const float* __restrict__ y, const float* __restrict__ W1,
    const float* __restrict__ b1, const float* __restrict__ W2,
    unsigned short* __restrict__ yb, unsigned short* __restrict__ W2b,
    unsigned short* __restrict__ W1b,
    unsigned short* __restrict__ Lb, unsigned short* __restrict__ Rt) {
    int bid = blockIdx.x;            // [0,480)
    int t = threadIdx.x;             // [0,256)
    int gid = bid * 256 + t;         // [0,122880)

    // ---- Phase 1a: RoPE -> yb (61440 pairs, <=1 per thread) ----
    if (gid < SDIM * HALF) {
        int s = gid / HALF;
        int p = gid - s * HALF;
        float invf = __expf(-(2.0f * (float)p / (float)HDIM) * 9.210340371976184f);
        float th = (float)s * invf;
        float c = cosf(th), sn = sinf(th);
        float y0 = y[s * HDIM + 2 * p], y1 = y[s * HDIM + 2 * p + 1];
        yb[s * HDIM + 2 * p]     = f2bf(y0 * c - y1 * sn);
        yb[s * HDIM + 2 * p + 1] = f2bf(y1 * c + y0 * sn);
    }
    // ---- Phase 1b: W2 -> W2b f16 [kg96][row272][8] (26112 slots) ----
    if (gid < 96 * OPAD) {
        int kg = gid / OPAD, row = gid - kg * OPAD;      // row fastest
        unsigned short o8[8];
        if (row < ODIM) {
            float4 a = *reinterpret_cast<const float4*>(W2 + row * HDIM + kg * 8);
            float4 b = *reinterpret_cast<const float4*>(W2 + row * HDIM + kg * 8 + 4);
            o8[0] = f2h(a.x); o8[1] = f2h(a.y); o8[2] = f2h(a.z); o8[3] = f2h(a.w);
            o8[4] = f2h(b.x); o8[5] = f2h(b.y); o8[6] = f2h(b.z); o8[7] = f2h(b.w);
        } else {
            #pragma unroll
            for (int e = 0; e < 8; ++e) o8[e] = 0;
        }
        *reinterpret_cast<uint4*>(W2b + ((size_t)kg * OPAD + row) * 8) =
            *reinterpret_cast<uint4*>(o8);
    }
    // ---- Phase 1c: W1 -> W1b bf16 [kg96][row1536][8] (147456 slots) ----
    for (int slot = gid; slot < 96 * 1536; slot += 480 * 256) {
        int kg = slot / 1536, row = slot - kg * 1536;    // row fastest
        const float* src = (row < 768) ? (W1 + row * 1536 + kg * 8)
                                       : (W1 + (row - 768) * 1536 + 768 + kg * 8);
        float4 a = *reinterpret_cast<const float4*>(src);
        float4 b = *reinterpret_cast<const float4*>(src + 4);
        unsigned short o8[8];
        o8[0] = f2bf(a.x); o8[1] = f2bf(a.y); o8[2] = f2bf(a.z); o8[3] = f2bf(a.w);
        o8[4] = f2bf(b.x); o8[5] = f2bf(b.y); o8[6] = f2bf(b.z); o8[7] = f2bf(b.w);
        *reinterpret_cast<uint4*>(W1b + ((size_t)kg * 1536 + row) * 8) =
            *reinterpret_cast<uint4*>(o8);
    }

    cg::this_grid().sync();

    // ---- Phase 2: lr3 unit per wave (waves 0-1 of each block; 960 units) --
    int w = t >> 6;
    if (w >= 2) return;
    int unit = bid * 2 + w;          // [0,960)
    int l = t & 63;
    int l16 = l & 15, qd = l >> 4;
    int mt = unit % 96;              // m-tile
    int sq = unit / 96;              // s-tile [0,10)
    int s0 = sq * 16 + l16;

    floatx4 acc = (floatx4){0.0f, 0.0f, 0.0f, 0.0f};
    const unsigned short* yrow0 = yb + s0 * HDIM;

    for (int ks = 0; ks < 24; ++ks) {
        int k = ks * 32 + qd * 8;
        int kg = ks * 4 + qd;
        union { uint4 u; short8 s; } bu0, au;
        bu0.u = *reinterpret_cast<const uint4*>(yrow0 + k);
        au.u = *reinterpret_cast<const uint4*>(
            W1b + ((size_t)kg * 1536 + mt * 16 + l16) * 8);
        acc = __builtin_amdgcn_mfma_f32_16x16x32_bf16(
            au.s, bu0.s, acc, 0, 0, 0);
    }

    int o2 = mt * 16 + qd * 4;
    unsigned short out4[4];
    if (o2 < 768) {
        #pragma unroll
        for (int r = 0; r < 4; ++r) out4[r] = f2h(acc[r]);
        *reinterpret_cast<uint2*>(Lb + s0 * HDIM + o2) =
            *reinterpret_cast<uint2*>(out4);
    } else {
        int ob = o2 - 768;               // [0,768), aligned to 4
        #pragma unroll
        for (int r = 0; r < 4; ++r)
            out4[r] = f2h(acc[r] + b1[ob + r]);
        // Rt[kg=ob>>3][s][e=ob&7], 4 consecutive e -> uint2 store
        *reinterpret_cast<uint2*>(
            Rt + ((size_t)(ob >> 3) * SDIM + s0) * 8 + (ob & 7)) =
            *reinterpret_cast<uint2*>(out4);
    }
}

// ---------------------------------------------------------------------------
// Kernel 1 (small-ws path only): prep without W1b.
// ---------------------------------------------------------------------------
__global__ __launch_bounds__(256) void prep_kernel(
    const float* __restrict__ y, const float* __restrict__ W1,
    const float* __restrict__ W2,
    unsigned short* __restrict__ yb, unsigned short* __restrict__ W2b,
    unsigned short* __restrict__ W1b, int do_w1b) {
    int bid = blockIdx.x;
    int t = threadIdx.x;
    if (bid < SDIM) {
        int s = bid;
        for (int p = t; p < HALF; p += 256) {
            float invf = __expf(-(2.0f * (float)p / (float)HDIM) * 9.210340371976184f);
            float th = (float)s * invf;
            float c = cosf(th), sn = sinf(th);
            float y0 = y[s * HDIM + 2 * p], y1 = y[s * HDIM + 2 * p + 1];
            yb[s * HDIM + 2 * p]     = f2bf(y0 * c - y1 * sn);
            yb[s * HDIM + 2 * p + 1] = f2bf(y1 * c + y0 * sn);
        }
    } else if (bid < SDIM + 102) {
        int idx = (bid - SDIM) * 256 + t;       // [0, 96*272)
        if (idx < 96 * OPAD) {
            int kg = idx / OPAD, row = idx - kg * OPAD;  // row fastest
            unsigned short o8[8];
            if (row < ODIM) {
                float4 a = *reinterpret_cast<const float4*>(W2 + row * HDIM + kg * 8);
                float4 b = *reinterpret_cast<const float4*>(W2 + row * HDIM + kg * 8 + 4);
                o8[0] = f2h(a.x); o8[1] = f2h(a.y); o8[2] = f2h(a.z); o8[3] = f2h(a.w);
                o8[4] = f2h(b.x); o8[5] = f2h(b.y); o8[6] = f2h(b.z); o8[7] = f2h(b.w);
            } else {
                #pragma unroll
                for (int e = 0; e < 8; ++e) o8[e] = 0;
            }
            *reinterpret_cast<uint4*>(W2b + ((size_t)kg * OPAD + row) * 8) =
                *reinterpret_cast<uint4*>(o8);
        }
    }
}

// ---------------------------------------------------------------------------
// Kernel 3 (small-ws path only): pure-VALU L/R (f16; R transposed).
// ---------------------------------------------------------------------------
__global__ __launch_bounds__(256) void lr_fallback_kernel(
    const unsigned short* __restrict__ yb, const float* __restrict__ W1,
    const float* __restrict__ b1,
    unsigned short* __restrict__ Lb, unsigned short* __restrict__ Rt) {
    int idx = blockIdx.x * 256 + threadIdx.x;   // [0, 160*1536)
    int s = idx / 1536;
    int o2 = idx - s * 1536;
    const unsigned short* yrow = yb + s * HDIM;
    if (o2 < 768) {
        const float* wp = W1 + o2 * 1536;
        float a0 = 0.0f;
        for (int k = 0; k < HDIM; ++k) a0 += q(wp[k]) * bf2f(yrow[k]);
        Lb[s * HDIM + o2] = f2h(a0);
    } else {
        int ob = o2 - 768;
        const float* wp = W1 + ob * 1536 + 768;
        float a0 = 0.0f;
        for (int k = 0; k < HDIM; ++k) a0 += q(wp[k]) * bf2f(yrow[k]);
        Rt[((size_t)(ob >> 3) * SDIM + s) * 8 + (ob & 7)] = f2h(a0 + b1[ob]);
    }
}

// ---------------------------------------------------------------------------
// Kernel 4 (R26, EXACT session-best 104.4, UNCHANGED): LDS-staged pair-GEMM.
// 8 waves, 2i x 32j, grid (80,5); W2b chunk + Rt slab double-buffered via
// fused STAGE; Lb rows staged once; VMEM/block 984 -> 459 (the only main
// win of the session). Structural search exhausted around this point:
// R9/R13 (occupancy/VMEM trades), R11 (ds-read dedup), R12/R20 (counted
// vmcnt), R22 (reg pipeline) all flat-or-worse. DO NOT TOUCH.
// ---------------------------------------------------------------------------
__global__ __launch_bounds__(512) void main_kernel(
    const unsigned short* __restrict__ Lb, const unsigned short* __restrict__ Rt,
    const unsigned short* __restrict__ W2b,
    const float* __restrict__ b2, float* __restrict__ out) {
    __shared__ __align__(16) unsigned char lds[2 * BUF_STRIDE + 3072];

    int w = threadIdx.x >> 6;        // 0..7
    int l = threadIdx.x & 63;
    int l16 = l & 15, qd = l >> 4;
    int jh = w & 1;                  // j-half
    int mq = w >> 1;                 // m-quarter
    int mt0 = mq * 4;
    int nmt = (mq == 3) ? 5 : 4;     // m-split 4/4/4/5 (17 tiles)
    int i0 = blockIdx.x * 2;
    int j0 = blockIdx.y * 32;
    int j = j0 + jh * 16 + l16;

    floatx4 acc[2][5];
    #pragma unroll
    for (int c = 0; c < 2; ++c)
        #pragma unroll
        for (int mtl = 0; mtl < 5; ++mtl)
            acc[c][mtl] = (floatx4){0.0f, 0.0f, 0.0f, 0.0f};

    const unsigned char* wsrc = reinterpret_cast<const unsigned char*>(W2b);
    const unsigned char* rtsrc = reinterpret_cast<const unsigned char*>(Rt);
    const unsigned char* lbsrc = reinterpret_cast<const unsigned char*>(Lb);

    // Fused STAGE of chunk ch into buffer b: 34 W2b segs + 4 Rt segs.
    auto STAGE = [&](int ch, int b) {
        unsigned char* lbuf = lds + b * BUF_STRIDE;
        #pragma unroll
        for (int it = 0; it < 5; ++it) {
            int seg = w + it * 8;
            if (seg < 34) {
                __builtin_amdgcn_global_load_lds(
                    (gl_u8*)(wsrc + (size_t)ch * CHUNK_BYTES + seg * 1024 + l * 16),
                    (lds_u8*)(lbuf + seg * 1024), 16, 0, 0);
            } else if (seg < 38) {
                int s2 = seg - 34;                 // 0..3
                int kgl = s2 * 2 + (l >> 5);       // kg within chunk, 0..7
                int jj = l & 31;
                __builtin_amdgcn_global_load_lds(
                    (gl_u8*)(rtsrc + (((size_t)(ch * 8 + kgl) * SDIM) + j0 + jj) * 16),
                    (lds_u8*)(lbuf + CHUNK_BYTES + s2 * 1024), 16, 0, 0);
            }
        }
    };

    // Lb rows (2 x 1536B = 3 segs), staged once by waves 0..2.
    if (w < 3) {
        int bofs = w * 1024 + l * 16;              // [0, 3072)
        int row = bofs >= 1536 ? 1 : 0;
        int off = bofs - row * 1536;
        __builtin_amdgcn_global_load_lds(
            (gl_u8*)(lbsrc + ((size_t)(i0 + row) * HDIM) * 2 + off),
            (lds_u8*)(lds + LB_OFF + w * 1024), 16, 0, 0);
    }
    STAGE(0, 0);
    __syncthreads();

    for (int kc = 0; kc < 12; ++kc) {
        int buf = kc & 1;
        if (kc < 11) STAGE(kc + 1, 1 - buf);   // async prefetch, overlaps compute
        #pragma unroll
        for (int ks = 0; ks < 2; ++ks) {
            int kgl = ks * 4 + qd;             // kg within chunk
            // ru from LDS slab: [kgl][jh*16+l16][8] f16
            half8 rh = *reinterpret_cast<const half8*>(
                lds + buf * BUF_STRIDE + CHUNK_BYTES +
                (kgl * 32 + jh * 16 + l16) * 16);
            int kb = (kc * 64 + ks * 32 + qd * 8) * 2;  // byte offset in Lb row
            half8 bfrag[2];
            #pragma unroll
            for (int c = 0; c < 2; ++c) {
                half8 lh = *reinterpret_cast<const half8*>(
                    lds + LB_OFF + c * 1536 + kb);      // 16-lane broadcast
                half8 hv = lh + rh;                     // v_pk_add_f16
                #pragma unroll
                for (int e = 0; e < 8; ++e)             // v_pk_max_f16
                    hv[e] = hv[e] > (_Float16)0.0f ? hv[e] : (_Float16)0.0f;
                bfrag[c] = hv;
            }
            int ldsbase = buf * BUF_STRIDE + (kgl * OPAD + l16) * 16;
            #pragma unroll
            for (int mtl = 0; mtl < 5; ++mtl) {
                if (mtl < nmt) {
                    half8 ah = *reinterpret_cast<const half8*>(
                        lds + ldsbase + (mt0 + mtl) * 256);
                    acc[0][mtl] = __builtin_amdgcn_mfma_f32_16x16x32_f16(
                        ah, bfrag[0], acc[0][mtl], 0, 0, 0);
                    acc[1][mtl] = __builtin_amdgcn_mfma_f32_16x16x32_f16(
                        ah, bfrag[1], acc[1][mtl], 0, 0, 0);
                }
            }
        }
        __syncthreads();   // prefetch landed + reads of buf done
    }

    #pragma unroll
    for (int c = 0; c < 2; ++c) {
        int i = i0 + c;
        #pragma unroll
        for (int mtl = 0; mtl < 5; ++mtl) {
            if (mtl < nmt) {
                int ob = (mt0 + mtl) * 16 + qd * 4;
                if (ob < ODIM) {
                    float4 bv = *reinterpret_cast<const float4*>(b2 + ob);
                    int rel = ob >> 2;
                    float4 v;
                    v.x = 1.0f / (1.0f + __expf(-(acc[c][mtl][0] + bv.x)));
                    v.y = 1.0f / (1.0f + __expf(-(acc[c][mtl][1] + bv.y)));
                    v.z = 1.0f / (1.0f + __expf(-(acc[c][mtl][2] + bv.z)));
                    v.w = 1.0f / (1.0f + __expf(-(acc[c][mtl][3] + bv.w)));
                    *reinterpret_cast<float4*>(
                        out + (((rel * SDIM) + i) * SDIM + j) * 4) = v;
                }
            }
        }
    }
}

__global__ void ws_too_small_kernel(float* out) { out[0] = 999.0f; }

extern "C" void kernel_launch(void* const* d_in, const int* in_sizes, int n_in,
                              void* d_out, int out_size, void* d_ws, size_t ws_size,
                              hipStream_t stream) {
    const float* y  = (const float*)d_in[0];
    // d_in[1] = event_idx : unused by the reference
    const float* W1 = (const float*)d_in[2];
    const float* b1 = (const float*)d_in[3];
    const float* W2 = (const float*)d_in[4];
    const float* b2 = (const float*)d_in[5];
    float* out = (float*)d_out;

    if (ws_size < (size_t)WS_SMALL) {
        ws_too_small_kernel<<<dim3(1), dim3(1), 0, stream>>>(out);
        return;
    }

    unsigned short* yb  = (unsigned short*)((char*)d_ws + 16);    // 160*768
    unsigned short* Lb  = yb + SDIM * HDIM;
    unsigned short* Rt  = Lb + SDIM * HDIM;                       // 96*160*8
    unsigned short* W2b = Rt + SDIM * HDIM;                       // 96*272*8
    unsigned short* W1b = W2b + 96 * OPAD * 8;                    // 96*1536*8

    if (ws_size >= (size_t)WS_BIG) {
        void* args[] = {(void*)&y, (void*)&W1, (void*)&b1, (void*)&W2,
                        (void*)&yb, (void*)&W2b, (void*)&W1b,
                        (void*)&Lb, (void*)&Rt};
        hipLaunchCooperativeKernel((const void*)fused_pl_kernel,
                                   dim3(480), dim3(256), args, 0, stream);
        main_kernel<<<dim3(80, 5), dim3(512), 0, stream>>>(Lb, Rt, W2b, b2, out);
    } else {
        prep_kernel<<<dim3(SDIM + 102), dim3(256), 0, stream>>>(
            y, W1, W2, yb, W2b, W1b, 0);
        lr_fallback_kernel<<<dim3(960), dim3(256), 0, stream>>>(yb, W1, b1, Lb, Rt);
        main_kernel<<<dim3(80, 5), dim3(512), 0, stream>>>(Lb, Rt, W2b, b2, out);
    }
}

// Round 15
// 104.772 us; speedup vs baseline: 1.6873x; 1.6873x over previous
//
#include <hip/hip_runtime.h>
#include <hip/hip_bf16.h>
#include <cstdint>

// Problem constants
#define SDIM 160
#define HDIM 768
#define HALF 384
#define ODIM 260
#define OPAD 272           // 17 * 16
#define CHUNK_BYTES 34816  // 8 kgroups * 272 rows * 16B (W2b chunk)
#define RT_CHUNK 4096      // 8 kgroups * 32 j * 16B (Rt chunk slab)
#define BUF_STRIDE 38912   // CHUNK_BYTES + RT_CHUNK
#define LB_OFF 77824       // 2 * BUF_STRIDE
// main LDS = 77824 + 3072 = 80896; 2 blocks/CU (161792 <= 163840)
// Workspace layout (bytes): pad@0(16) yb@16 Lb@245776 Rt@491536 W2b@737296
//                           W1b@1155088 end@3514384
#define WS_SMALL 1155088
#define WS_BIG   3514384

typedef __attribute__((ext_vector_type(8))) short short8;
typedef __attribute__((ext_vector_type(4))) float floatx4;
typedef _Float16 half8 __attribute__((ext_vector_type(8)));

typedef const __attribute__((address_space(1))) unsigned char gl_u8;
typedef __attribute__((address_space(3))) unsigned char lds_u8;

static __device__ __forceinline__ float bf2f(unsigned short u) {
    union { unsigned int i; float f; } v; v.i = ((unsigned int)u) << 16; return v.f;
}
static __device__ __forceinline__ unsigned short f2bf(float x) {
    __hip_bfloat16 h = __float2bfloat16(x);
    return *reinterpret_cast<unsigned short*>(&h);
}
static __device__ __forceinline__ unsigned short f2h(float x) {
    _Float16 h = (_Float16)x;
    return *reinterpret_cast<unsigned short*>(&h);
}
static __device__ __forceinline__ float q(float x) { return bf2f(f2bf(x)); }

// ---------------------------------------------------------------------------
// Kernel 1 (R4-proven): RoPE(y) -> yb bf16; W2 -> W2b f16 [kg96][row272][8];
// (big path) W1 -> W1b bf16 [kg96][row1536][8]. Row-fastest mappings ->
// coalesced 16B stores.
// ---------------------------------------------------------------------------
__global__ __launch_bounds__(256) void prep_kernel(
    const float* __restrict__ y, const float* __restrict__ W1,
    const float* __restrict__ W2,
    unsigned short* __restrict__ yb, unsigned short* __restrict__ W2b,
    unsigned short* __restrict__ W1b, int do_w1b) {
    int bid = blockIdx.x;
    int t = threadIdx.x;
    if (bid < SDIM) {
        int s = bid;
        for (int p = t; p < HALF; p += 256) {
            float invf = __expf(-(2.0f * (float)p / (float)HDIM) * 9.210340371976184f);
            float th = (float)s * invf;
            float c = cosf(th), sn = sinf(th);
            float y0 = y[s * HDIM + 2 * p], y1 = y[s * HDIM + 2 * p + 1];
            yb[s * HDIM + 2 * p]     = f2bf(y0 * c - y1 * sn);
            yb[s * HDIM + 2 * p + 1] = f2bf(y1 * c + y0 * sn);
        }
    } else if (bid < SDIM + 102) {
        int idx = (bid - SDIM) * 256 + t;       // [0, 96*272)
        if (idx < 96 * OPAD) {
            int kg = idx / OPAD, row = idx - kg * OPAD;  // row fastest
            unsigned short o8[8];
            if (row < ODIM) {
                float4 a = *reinterpret_cast<const float4*>(W2 + row * HDIM + kg * 8);
                float4 b = *reinterpret_cast<const float4*>(W2 + row * HDIM + kg * 8 + 4);
                o8[0] = f2h(a.x); o8[1] = f2h(a.y); o8[2] = f2h(a.z); o8[3] = f2h(a.w);
                o8[4] = f2h(b.x); o8[5] = f2h(b.y); o8[6] = f2h(b.z); o8[7] = f2h(b.w);
            } else {
                #pragma unroll
                for (int e = 0; e < 8; ++e) o8[e] = 0;
            }
            *reinterpret_cast<uint4*>(W2b + ((size_t)kg * OPAD + row) * 8) =
                *reinterpret_cast<uint4*>(o8);
        }
    } else if (do_w1b) {
        int idx = (bid - SDIM - 102) * 256 + t; // [0, 96*1536)
        int kg = idx / 1536, row = idx - kg * 1536;      // row fastest
        const float* src = (row < 768) ? (W1 + row * 1536 + kg * 8)
                                       : (W1 + (row - 768) * 1536 + 768 + kg * 8);
        float4 a = *reinterpret_cast<const float4*>(src);
        float4 b = *reinterpret_cast<const float4*>(src + 4);
        unsigned short o8[8];
        o8[0] = f2bf(a.x); o8[1] = f2bf(a.y); o8[2] = f2bf(a.z); o8[3] = f2bf(a.w);
        o8[4] = f2bf(b.x); o8[5] = f2bf(b.y); o8[6] = f2bf(b.z); o8[7] = f2bf(b.w);
        *reinterpret_cast<uint4*>(W1b + ((size_t)kg * 1536 + row) * 8) =
            *reinterpret_cast<uint4*>(o8);
    }
}

// ---------------------------------------------------------------------------
// Kernel 2 (R4-proven): barrier-free L/R GEMM from W1b (L2-resident).
// Grid (96,10): one 16-row s-tile per wave, 960 waves (~3.75/CU).
// ---------------------------------------------------------------------------
__global__ __launch_bounds__(64, 2) void lr3_kernel(
    const unsigned short* __restrict__ yb, const unsigned short* __restrict__ W1b,
    const float* __restrict__ b1,
    unsigned short* __restrict__ Lb, unsigned short* __restrict__ Rt) {
    int l = threadIdx.x & 63;
    int l16 = l & 15, qd = l >> 4;
    int mt = blockIdx.x;                 // m-tile [0,96)
    int sq = blockIdx.y;                 // s-tile [0,10)
    int s0 = sq * 16 + l16;

    floatx4 acc = (floatx4){0.0f, 0.0f, 0.0f, 0.0f};

    const unsigned short* yrow0 = yb + s0 * HDIM;

    for (int ks = 0; ks < 24; ++ks) {
        int k = ks * 32 + qd * 8;
        int kg = ks * 4 + qd;
        union { uint4 u; short8 s; } bu0, au;
        bu0.u = *reinterpret_cast<const uint4*>(yrow0 + k);
        au.u = *reinterpret_cast<const uint4*>(
            W1b + ((size_t)kg * 1536 + mt * 16 + l16) * 8);
        acc = __builtin_amdgcn_mfma_f32_16x16x32_bf16(
            au.s, bu0.s, acc, 0, 0, 0);
    }

    int o2 = mt * 16 + qd * 4;
    int s_out = sq * 16 + l16;
    unsigned short out4[4];
    if (o2 < 768) {
        #pragma unroll
        for (int r = 0; r < 4; ++r) out4[r] = f2h(acc[r]);
        *reinterpret_cast<uint2*>(Lb + s_out * HDIM + o2) =
            *reinterpret_cast<uint2*>(out4);
    } else {
        int ob = o2 - 768;               // [0,768), aligned to 4
        #pragma unroll
        for (int r = 0; r < 4; ++r)
            out4[r] = f2h(acc[r] + b1[ob + r]);
        // Rt[kg=ob>>3][s][e=ob&7], 4 consecutive e -> uint2 store
        *reinterpret_cast<uint2*>(
            Rt + ((size_t)(ob >> 3) * SDIM + s_out) * 8 + (ob & 7)) =
            *reinterpret_cast<uint2*>(out4);
    }
}

// ---------------------------------------------------------------------------
// Kernel 3 (small-ws path only): pure-VALU L/R (f16; R transposed).
// ---------------------------------------------------------------------------
__global__ __launch_bounds__(256) void lr_fallback_kernel(
    const unsigned short* __restrict__ yb, const float* __restrict__ W1,
    const float* __restrict__ b1,
    unsigned short* __restrict__ Lb, unsigned short* __restrict__ Rt) {
    int idx = blockIdx.x * 256 + threadIdx.x;   // [0, 160*1536)
    int s = idx / 1536;
    int o2 = idx - s * 1536;
    const unsigned short* yrow = yb + s * HDIM;
    if (o2 < 768) {
        const float* wp = W1 + o2 * 1536;
        float a0 = 0.0f;
        for (int k = 0; k < HDIM; ++k) a0 += q(wp[k]) * bf2f(yrow[k]);
        Lb[s * HDIM + o2] = f2h(a0);
    } else {
        int ob = o2 - 768;
        const float* wp = W1 + ob * 1536 + 768;
        float a0 = 0.0f;
        for (int k = 0; k < HDIM; ++k) a0 += q(wp[k]) * bf2f(yrow[k]);
        Rt[((size_t)(ob >> 3) * SDIM + s) * 8 + (ob & 7)] = f2h(a0 + b1[ob]);
    }
}

// ---------------------------------------------------------------------------
// Kernel 4 (R26, EXACT session-best 104.4): LDS-staged pair-GEMM.
// 8 waves, 2i x 32j, grid (80,5); W2b chunk + Rt slab double-buffered via
// fused STAGE; Lb rows staged once; VMEM/block 984 -> 459 (the only main
// win of the session, -5.1us). Structural search EXHAUSTED around this
// point: R9/R13 (occupancy/VMEM trades), R11 (ds-read dedup), R12/R20
// (counted vmcnt), R22 (reg pipeline), R14 (coop fusion: grid.sync costs
// ~50us on MI355X -- never use) all flat-or-worse. DO NOT TOUCH.
// ---------------------------------------------------------------------------
__global__ __launch_bounds__(512) void main_kernel(
    const unsigned short* __restrict__ Lb, const unsigned short* __restrict__ Rt,
    const unsigned short* __restrict__ W2b,
    const float* __restrict__ b2, float* __restrict__ out) {
    __shared__ __align__(16) unsigned char lds[2 * BUF_STRIDE + 3072];

    int w = threadIdx.x >> 6;        // 0..7
    int l = threadIdx.x & 63;
    int l16 = l & 15, qd = l >> 4;
    int jh = w & 1;                  // j-half
    int mq = w >> 1;                 // m-quarter
    int mt0 = mq * 4;
    int nmt = (mq == 3) ? 5 : 4;     // m-split 4/4/4/5 (17 tiles)
    int i0 = blockIdx.x * 2;
    int j0 = blockIdx.y * 32;
    int j = j0 + jh * 16 + l16;

    floatx4 acc[2][5];
    #pragma unroll
    for (int c = 0; c < 2; ++c)
        #pragma unroll
        for (int mtl = 0; mtl < 5; ++mtl)
            acc[c][mtl] = (floatx4){0.0f, 0.0f, 0.0f, 0.0f};

    const unsigned char* wsrc = reinterpret_cast<const unsigned char*>(W2b);
    const unsigned char* rtsrc = reinterpret_cast<const unsigned char*>(Rt);
    const unsigned char* lbsrc = reinterpret_cast<const unsigned char*>(Lb);

    // Fused STAGE of chunk ch into buffer b: 34 W2b segs + 4 Rt segs.
    auto STAGE = [&](int ch, int b) {
        unsigned char* lbuf = lds + b * BUF_STRIDE;
        #pragma unroll
        for (int it = 0; it < 5; ++it) {
            int seg = w + it * 8;
            if (seg < 34) {
                __builtin_amdgcn_global_load_lds(
                    (gl_u8*)(wsrc + (size_t)ch * CHUNK_BYTES + seg * 1024 + l * 16),
                    (lds_u8*)(lbuf + seg * 1024), 16, 0, 0);
            } else if (seg < 38) {
                int s2 = seg - 34;                 // 0..3
                int kgl = s2 * 2 + (l >> 5);       // kg within chunk, 0..7
                int jj = l & 31;
                __builtin_amdgcn_global_load_lds(
                    (gl_u8*)(rtsrc + (((size_t)(ch * 8 + kgl) * SDIM) + j0 + jj) * 16),
                    (lds_u8*)(lbuf + CHUNK_BYTES + s2 * 1024), 16, 0, 0);
            }
        }
    };

    // Lb rows (2 x 1536B = 3 segs), staged once by waves 0..2.
    if (w < 3) {
        int bofs = w * 1024 + l * 16;              // [0, 3072)
        int row = bofs >= 1536 ? 1 : 0;
        int off = bofs - row * 1536;
        __builtin_amdgcn_global_load_lds(
            (gl_u8*)(lbsrc + ((size_t)(i0 + row) * HDIM) * 2 + off),
            (lds_u8*)(lds + LB_OFF + w * 1024), 16, 0, 0);
    }
    STAGE(0, 0);
    __syncthreads();

    for (int kc = 0; kc < 12; ++kc) {
        int buf = kc & 1;
        if (kc < 11) STAGE(kc + 1, 1 - buf);   // async prefetch, overlaps compute
        #pragma unroll
        for (int ks = 0; ks < 2; ++ks) {
            int kgl = ks * 4 + qd;             // kg within chunk
            // ru from LDS slab: [kgl][jh*16+l16][8] f16
            half8 rh = *reinterpret_cast<const half8*>(
                lds + buf * BUF_STRIDE + CHUNK_BYTES +
                (kgl * 32 + jh * 16 + l16) * 16);
            int kb = (kc * 64 + ks * 32 + qd * 8) * 2;  // byte offset in Lb row
            half8 bfrag[2];
            #pragma unroll
            for (int c = 0; c < 2; ++c) {
                half8 lh = *reinterpret_cast<const half8*>(
                    lds + LB_OFF + c * 1536 + kb);      // 16-lane broadcast
                half8 hv = lh + rh;                     // v_pk_add_f16
                #pragma unroll
                for (int e = 0; e < 8; ++e)             // v_pk_max_f16
                    hv[e] = hv[e] > (_Float16)0.0f ? hv[e] : (_Float16)0.0f;
                bfrag[c] = hv;
            }
            int ldsbase = buf * BUF_STRIDE + (kgl * OPAD + l16) * 16;
            #pragma unroll
            for (int mtl = 0; mtl < 5; ++mtl) {
                if (mtl < nmt) {
                    half8 ah = *reinterpret_cast<const half8*>(
                        lds + ldsbase + (mt0 + mtl) * 256);
                    acc[0][mtl] = __builtin_amdgcn_mfma_f32_16x16x32_f16(
                        ah, bfrag[0], acc[0][mtl], 0, 0, 0);
                    acc[1][mtl] = __builtin_amdgcn_mfma_f32_16x16x32_f16(
                        ah, bfrag[1], acc[1][mtl], 0, 0, 0);
                }
            }
        }
        __syncthreads();   // prefetch landed + reads of buf done
    }

    #pragma unroll
    for (int c = 0; c < 2; ++c) {
        int i = i0 + c;
        #pragma unroll
        for (int mtl = 0; mtl < 5; ++mtl) {
            if (mtl < nmt) {
                int ob = (mt0 + mtl) * 16 + qd * 4;
                if (ob < ODIM) {
                    float4 bv = *reinterpret_cast<const float4*>(b2 + ob);
                    int rel = ob >> 2;
                    float4 v;
                    v.x = 1.0f / (1.0f + __expf(-(acc[c][mtl][0] + bv.x)));
                    v.y = 1.0f / (1.0f + __expf(-(acc[c][mtl][1] + bv.y)));
                    v.z = 1.0f / (1.0f + __expf(-(acc[c][mtl][2] + bv.z)));
                    v.w = 1.0f / (1.0f + __expf(-(acc[c][mtl][3] + bv.w)));
                    *reinterpret_cast<float4*>(
                        out + (((rel * SDIM) + i) * SDIM + j) * 4) = v;
                }
            }
        }
    }
}

__global__ void ws_too_small_kernel(float* out) { out[0] = 999.0f; }

extern "C" void kernel_launch(void* const* d_in, const int* in_sizes, int n_in,
                              void* d_out, int out_size, void* d_ws, size_t ws_size,
                              hipStream_t stream) {
    const float* y  = (const float*)d_in[0];
    // d_in[1] = event_idx : unused by the reference
    const float* W1 = (const float*)d_in[2];
    const float* b1 = (const float*)d_in[3];
    const float* W2 = (const float*)d_in[4];
    const float* b2 = (const float*)d_in[5];
    float* out = (float*)d_out;

    if (ws_size < (size_t)WS_SMALL) {
        ws_too_small_kernel<<<dim3(1), dim3(1), 0, stream>>>(out);
        return;
    }

    unsigned short* yb  = (unsigned short*)((char*)d_ws + 16);    // 160*768
    unsigned short* Lb  = yb + SDIM * HDIM;
    unsigned short* Rt  = Lb + SDIM * HDIM;                       // 96*160*8
    unsigned short* W2b = Rt + SDIM * HDIM;                       // 96*272*8
    unsigned short* W1b = W2b + 96 * OPAD * 8;                    // 96*1536*8

    if (ws_size >= (size_t)WS_BIG) {
        prep_kernel<<<dim3(SDIM + 102 + 576), dim3(256), 0, stream>>>(
            y, W1, W2, yb, W2b, W1b, 1);
        lr3_kernel<<<dim3(96, 10), dim3(64), 0, stream>>>(yb, W1b, b1, Lb, Rt);
        main_kernel<<<dim3(80, 5), dim3(512), 0, stream>>>(Lb, Rt, W2b, b2, out);
    } else {
        prep_kernel<<<dim3(SDIM + 102), dim3(256), 0, stream>>>(
            y, W1, W2, yb, W2b, W1b, 0);
        lr_fallback_kernel<<<dim3(960), dim3(256), 0, stream>>>(yb, W1, b1, Lb, Rt);
        main_kernel<<<dim3(80, 5), dim3(512), 0, stream>>>(Lb, Rt, W2b, b2, out);
    }
}